// Round 1
// baseline (217.405 us; speedup 1.0000x reference)
//
#include <hip/hip_runtime.h>
#include <hip/hip_bf16.h>

#define D_FEAT 256
#define BM 128
#define BK 64

typedef float f32x4 __attribute__((ext_vector_type(4)));
typedef short bf16x8 __attribute__((ext_vector_type(8)));

// round-to-nearest-even f32 -> bf16 bits
__device__ __forceinline__ unsigned short f2bf(float f) {
  unsigned int u = __float_as_uint(f);
  u += 0x7fffu + ((u >> 16) & 1u);
  return (unsigned short)(u >> 16);
}

// Convert one input matrix to bf16 and compute exact f32 row sq-norms.
// One wave per row; lane loads float4 (16B), stores ushort4 (8B).
__global__ void prep_kernel(const float* __restrict__ src,
                            unsigned short* __restrict__ dst,
                            float* __restrict__ sq, int nrows) {
  int row = blockIdx.x * 4 + (threadIdx.x >> 6);
  int lane = threadIdx.x & 63;
  if (row >= nrows) return;
  float4 v = reinterpret_cast<const float4*>(src)[row * (D_FEAT / 4) + lane];
  float s = v.x * v.x + v.y * v.y + v.z * v.z + v.w * v.w;
  ushort4 o;
  o.x = f2bf(v.x); o.y = f2bf(v.y); o.z = f2bf(v.z); o.w = f2bf(v.w);
  reinterpret_cast<ushort4*>(dst)[row * (D_FEAT / 4) + lane] = o;
#pragma unroll
  for (int off = 32; off > 0; off >>= 1) s += __shfl_down(s, off);
  if (lane == 0) sq[row] = s;
}

// Fused pair-tile kernel: bf16 MFMA Gram tile + multi-bandwidth gaussian
// epilogue + reduction. Grid covers xy (full) + xx/yy (upper triangular).
__global__ __launch_bounds__(256, 2)
void mmd_pair_kernel(const unsigned short* __restrict__ Xb,
                     const unsigned short* __restrict__ Yb,
                     const float* __restrict__ xsq,
                     const float* __restrict__ ysq,
                     double* __restrict__ accum,
                     int ntx, int nty, int num_xy, int num_tri_x) {
  __shared__ unsigned short As[BM * BK];
  __shared__ unsigned short Bs[BM * BK];
  __shared__ float wsum[4];

  int b = blockIdx.x;
  const unsigned short *Ap, *Bp;
  const float *asq, *bsq;
  int ti, tj, accIdx;
  float wt = 1.0f;
  bool maskDiag = false;

  if (b < num_xy) {
    ti = b / nty; tj = b % nty;
    Ap = Xb; Bp = Yb; asq = xsq; bsq = ysq; accIdx = 2;
  } else {
    int r, nt;
    if (b < num_xy + num_tri_x) {
      r = b - num_xy; nt = ntx; Ap = Xb; Bp = Xb; asq = xsq; bsq = xsq; accIdx = 0;
    } else {
      r = b - num_xy - num_tri_x; nt = nty; Ap = Yb; Bp = Yb; asq = ysq; bsq = ysq; accIdx = 1;
    }
    ti = 0;
    while (r >= nt - ti) { r -= nt - ti; ++ti; }  // upper-tri decode, ti<=tj
    tj = ti + r;
    if (ti == tj) maskDiag = true; else wt = 2.0f;
  }

  int tid = threadIdx.x;
  int wid = tid >> 6, lane = tid & 63;
  int wr = wid >> 1, wc = wid & 1;          // 2x2 wave grid, 64x64 per wave

  f32x4 acc[4][4];
#pragma unroll
  for (int m = 0; m < 4; ++m)
#pragma unroll
    for (int n = 0; n < 4; ++n) acc[m][n] = (f32x4){0.f, 0.f, 0.f, 0.f};

  const char* Abase = (const char*)Ap + (size_t)ti * BM * (D_FEAT * 2);
  const char* Bbase = (const char*)Bp + (size_t)tj * BM * (D_FEAT * 2);
  // staging geometry: chunk = 1KB = 8 rows x 128B; lane covers 16B
  int srow = lane >> 3;                     // row within chunk (0..7)
  int ssw = ((lane & 7) * 16) ^ (srow << 4); // pre-swizzled source col-byte

  for (int ks = 0; ks < D_FEAT / BK; ++ks) {
#pragma unroll
    for (int q = 0; q < 4; ++q) {
      int c = wid * 4 + q;                  // chunk id (0..15)
      size_t roff = (size_t)(c * 8 + srow) * (D_FEAT * 2) + ks * (BK * 2) + ssw;
      __builtin_amdgcn_global_load_lds(
          (const __attribute__((address_space(1))) unsigned int*)(Abase + roff),
          (__attribute__((address_space(3))) unsigned int*)((char*)As + c * 1024),
          16, 0, 0);
      __builtin_amdgcn_global_load_lds(
          (const __attribute__((address_space(1))) unsigned int*)(Bbase + roff),
          (__attribute__((address_space(3))) unsigned int*)((char*)Bs + c * 1024),
          16, 0, 0);
    }
    __syncthreads();
#pragma unroll
    for (int kk = 0; kk < 2; ++kk) {
      bf16x8 af[4], bfr[4];
#pragma unroll
      for (int m = 0; m < 4; ++m) {
        int rr = wr * 64 + m * 16 + (lane & 15);
        int colb = kk * 64 + (lane >> 4) * 16;
        int addr = rr * 128 + (colb ^ ((rr & 7) << 4));
        af[m] = *(const bf16x8*)((const char*)As + addr);
      }
#pragma unroll
      for (int n = 0; n < 4; ++n) {
        int rr = wc * 64 + n * 16 + (lane & 15);
        int colb = kk * 64 + (lane >> 4) * 16;
        int addr = rr * 128 + (colb ^ ((rr & 7) << 4));
        bfr[n] = *(const bf16x8*)((const char*)Bs + addr);
      }
#pragma unroll
      for (int m = 0; m < 4; ++m)
#pragma unroll
        for (int n = 0; n < 4; ++n)
          acc[m][n] = __builtin_amdgcn_mfma_f32_16x16x32_bf16(af[m], bfr[n], acc[m][n], 0, 0, 0);
    }
    __syncthreads();
  }

  // epilogue: d2 = |x|^2 + |y|^2 - 2*dot, 5-bandwidth gaussian sum
  // exp(c*d2) = exp2(d2 * c*log2(e)), c = -1/(2*bw^2)
  const float C0 = (float)(-18.033688010972094);   // bw 0.2
  const float C1 = (float)(-2.8853900817555354);   // bw 0.5
  const float C2 = (float)(-0.7213475204388839);   // bw 1.0
  const float C3 = (float)(-0.18033688010972097);  // bw 2.0
  const float C4 = (float)(-0.028853900817555354); // bw 5.0

  int rbase = ti * BM + wr * 64 + (lane >> 4) * 4;
  int cbase = tj * BM + wc * 64 + (lane & 15);
  float xsr[4][4], ysc[4];
#pragma unroll
  for (int m = 0; m < 4; ++m)
#pragma unroll
    for (int j = 0; j < 4; ++j) xsr[m][j] = asq[rbase + m * 16 + j];
#pragma unroll
  for (int n = 0; n < 4; ++n) ysc[n] = bsq[cbase + n * 16];

  float sum = 0.f;
#pragma unroll
  for (int m = 0; m < 4; ++m)
#pragma unroll
    for (int n = 0; n < 4; ++n)
#pragma unroll
      for (int j = 0; j < 4; ++j) {
        float xy = acc[m][n][j];
        float d2 = fmaxf(xsr[m][j] + ysc[n] - 2.0f * xy, 0.0f);
        float e = exp2f(d2 * C0) + exp2f(d2 * C1) + exp2f(d2 * C2) +
                  exp2f(d2 * C3) + exp2f(d2 * C4);
        bool skip = maskDiag && ((rbase + m * 16 + j) == (cbase + n * 16));
        sum += skip ? 0.0f : e;
      }

#pragma unroll
  for (int off = 32; off > 0; off >>= 1) sum += __shfl_down(sum, off);
  if (lane == 0) wsum[wid] = sum;
  __syncthreads();
  if (tid == 0) {
    double t = (double)((wsum[0] + wsum[1]) + (wsum[2] + wsum[3])) * (double)wt;
    atomicAdd(&accum[accIdx], t);
  }
}

__global__ void finalize_kernel(const double* __restrict__ accum,
                                float* __restrict__ out, int N, int M) {
  double dN = (double)N, dM = (double)M;
  double v = accum[0] / (5.0 * dN * dN) + accum[1] / (5.0 * dM * dM)
           - 2.0 * accum[2] / (5.0 * dN * dM) + 1.0 / dN + 1.0 / dM;
  out[0] = (float)v;
}

extern "C" void kernel_launch(void* const* d_in, const int* in_sizes, int n_in,
                              void* d_out, int out_size, void* d_ws, size_t ws_size,
                              hipStream_t stream) {
  const float* s = (const float*)d_in[0];
  const float* t = (const float*)d_in[1];
  int N = in_sizes[0] / D_FEAT;
  int M = in_sizes[1] / D_FEAT;

  char* ws = (char*)d_ws;
  unsigned short* Xb = (unsigned short*)ws;
  unsigned short* Yb = Xb + (size_t)N * D_FEAT;
  float* xsq = (float*)(Yb + (size_t)M * D_FEAT);
  float* ysq = xsq + N;
  double* accum = (double*)(((uintptr_t)(ysq + M) + 15) & ~(uintptr_t)15);

  hipMemsetAsync(accum, 0, 3 * sizeof(double), stream);
  prep_kernel<<<(N + 3) / 4, 256, 0, stream>>>(s, Xb, xsq, N);
  prep_kernel<<<(M + 3) / 4, 256, 0, stream>>>(t, Yb, ysq, M);

  int ntx = N / BM, nty = M / BM;
  int num_xy = ntx * nty;
  int num_tri_x = ntx * (ntx + 1) / 2;
  int num_tri_y = nty * (nty + 1) / 2;
  int grid = num_xy + num_tri_x + num_tri_y;
  mmd_pair_kernel<<<grid, 256, 0, stream>>>(Xb, Yb, xsq, ysq, accum,
                                            ntx, nty, num_xy, num_tri_x);
  finalize_kernel<<<1, 1, 0, stream>>>(accum, (float*)d_out, N, M);
}

// Round 2
// 138.886 us; speedup vs baseline: 1.5654x; 1.5654x over previous
//
#include <hip/hip_runtime.h>
#include <hip/hip_bf16.h>

#define D_FEAT 256
#define BM 128
#define BK 64

typedef float f32x4 __attribute__((ext_vector_type(4)));
typedef short bf16x8 __attribute__((ext_vector_type(8)));

// round-to-nearest-even f32 -> bf16 bits
__device__ __forceinline__ unsigned short f2bf(float f) {
  unsigned int u = __float_as_uint(f);
  u += 0x7fffu + ((u >> 16) & 1u);
  return (unsigned short)(u >> 16);
}

// raw v_exp_f32 (base-2). Input always <= 0 here; deep underflow -> 0.
__device__ __forceinline__ float exp2r(float x) {
  return __builtin_amdgcn_exp2f(x);
}

// Convert one input matrix to bf16 and compute exact f32 row sq-norms.
__global__ void prep_kernel(const float* __restrict__ src,
                            unsigned short* __restrict__ dst,
                            float* __restrict__ sq, int nrows) {
  int row = blockIdx.x * 4 + (threadIdx.x >> 6);
  int lane = threadIdx.x & 63;
  if (row >= nrows) return;
  float4 v = reinterpret_cast<const float4*>(src)[row * (D_FEAT / 4) + lane];
  float s = v.x * v.x + v.y * v.y + v.z * v.z + v.w * v.w;
  ushort4 o;
  o.x = f2bf(v.x); o.y = f2bf(v.y); o.z = f2bf(v.z); o.w = f2bf(v.w);
  reinterpret_cast<ushort4*>(dst)[row * (D_FEAT / 4) + lane] = o;
#pragma unroll
  for (int off = 32; off > 0; off >>= 1) s += __shfl_down(s, off);
  if (lane == 0) sq[row] = s;
}

// Fused pair-tile kernel: bf16 MFMA Gram tile + multi-bandwidth gaussian
// epilogue + reduction. Grid covers xy (full) + xx/yy (upper triangular).
__global__ __launch_bounds__(256, 2)
void mmd_pair_kernel(const unsigned short* __restrict__ Xb,
                     const unsigned short* __restrict__ Yb,
                     const float* __restrict__ xsq,
                     const float* __restrict__ ysq,
                     double* __restrict__ accum,
                     int ntx, int nty, int num_xy, int num_tri_x) {
  __shared__ unsigned short As[BM * BK];
  __shared__ unsigned short Bs[BM * BK];
  __shared__ float wsum[4];

  int b = blockIdx.x;
  const unsigned short *Ap, *Bp;
  const float *asq, *bsq;
  int ti, tj, accIdx;
  float wt = 1.0f;
  bool maskDiag = false;

  if (b < num_xy) {
    ti = b / nty; tj = b % nty;
    Ap = Xb; Bp = Yb; asq = xsq; bsq = ysq; accIdx = 2;
  } else {
    int r, nt;
    if (b < num_xy + num_tri_x) {
      r = b - num_xy; nt = ntx; Ap = Xb; Bp = Xb; asq = xsq; bsq = xsq; accIdx = 0;
    } else {
      r = b - num_xy - num_tri_x; nt = nty; Ap = Yb; Bp = Yb; asq = ysq; bsq = ysq; accIdx = 1;
    }
    ti = 0;
    while (r >= nt - ti) { r -= nt - ti; ++ti; }  // upper-tri decode, ti<=tj
    tj = ti + r;
    if (ti == tj) maskDiag = true; else wt = 2.0f;
  }

  int tid = threadIdx.x;
  int wid = tid >> 6, lane = tid & 63;
  int wr = wid >> 1, wc = wid & 1;          // 2x2 wave grid, 64x64 per wave

  f32x4 acc[4][4];
#pragma unroll
  for (int m = 0; m < 4; ++m)
#pragma unroll
    for (int n = 0; n < 4; ++n) acc[m][n] = (f32x4){0.f, 0.f, 0.f, 0.f};

  const char* Abase = (const char*)Ap + (size_t)ti * BM * (D_FEAT * 2);
  const char* Bbase = (const char*)Bp + (size_t)tj * BM * (D_FEAT * 2);
  // staging geometry: chunk = 1KB = 8 rows x 128B; lane covers 16B
  int srow = lane >> 3;                     // row within chunk (0..7)
  int ssw = ((lane & 7) * 16) ^ (srow << 4); // pre-swizzled source col-byte

  for (int ks = 0; ks < D_FEAT / BK; ++ks) {
#pragma unroll
    for (int q = 0; q < 4; ++q) {
      int c = wid * 4 + q;                  // chunk id (0..15)
      size_t roff = (size_t)(c * 8 + srow) * (D_FEAT * 2) + ks * (BK * 2) + ssw;
      __builtin_amdgcn_global_load_lds(
          (const __attribute__((address_space(1))) unsigned int*)(Abase + roff),
          (__attribute__((address_space(3))) unsigned int*)((char*)As + c * 1024),
          16, 0, 0);
      __builtin_amdgcn_global_load_lds(
          (const __attribute__((address_space(1))) unsigned int*)(Bbase + roff),
          (__attribute__((address_space(3))) unsigned int*)((char*)Bs + c * 1024),
          16, 0, 0);
    }
    __syncthreads();
#pragma unroll
    for (int kk = 0; kk < 2; ++kk) {
      bf16x8 af[4], bfr[4];
#pragma unroll
      for (int m = 0; m < 4; ++m) {
        int rr = wr * 64 + m * 16 + (lane & 15);
        int colb = kk * 64 + (lane >> 4) * 16;
        int addr = rr * 128 + (colb ^ ((rr & 7) << 4));
        af[m] = *(const bf16x8*)((const char*)As + addr);
      }
#pragma unroll
      for (int n = 0; n < 4; ++n) {
        int rr = wc * 64 + n * 16 + (lane & 15);
        int colb = kk * 64 + (lane >> 4) * 16;
        int addr = rr * 128 + (colb ^ ((rr & 7) << 4));
        bfr[n] = *(const bf16x8*)((const char*)Bs + addr);
      }
#pragma unroll
      for (int m = 0; m < 4; ++m)
#pragma unroll
        for (int n = 0; n < 4; ++n)
          acc[m][n] = __builtin_amdgcn_mfma_f32_16x16x32_bf16(af[m], bfr[n], acc[m][n], 0, 0, 0);
    }
    __syncthreads();
  }

  // epilogue: d2 = |x|^2 + |y|^2 - 2*dot, 5-bandwidth gaussian sum
  // exp(c*d2) = exp2(d2 * c*log2(e)), c = -1/(2*bw^2)
  const float C0 = (float)(-18.033688010972094);   // bw 0.2
  const float C1 = (float)(-2.8853900817555354);   // bw 0.5
  const float C2 = (float)(-0.7213475204388839);   // bw 1.0
  const float C3 = (float)(-0.18033688010972097);  // bw 2.0
  const float C4 = (float)(-0.028853900817555354); // bw 5.0
  // For d2 > 210: C0..C2 args < -151 -> exactly 0 in f32 (below denorm min).
  // Bulk off-diagonal d2 ~ 512, so the 3-exp tail is wave-uniformly skipped.

  int rbase = ti * BM + wr * 64 + (lane >> 4) * 4;
  int cbase = tj * BM + wc * 64 + (lane & 15);
  float xsr[4][4], ysc[4];
#pragma unroll
  for (int m = 0; m < 4; ++m)
#pragma unroll
    for (int j = 0; j < 4; ++j) xsr[m][j] = asq[rbase + m * 16 + j];
#pragma unroll
  for (int n = 0; n < 4; ++n) ysc[n] = bsq[cbase + n * 16];

  float sum = 0.f;
#pragma unroll
  for (int m = 0; m < 4; ++m)
#pragma unroll
    for (int n = 0; n < 4; ++n)
#pragma unroll
      for (int j = 0; j < 4; ++j) {
        float xy = acc[m][n][j];
        float d2 = fmaxf(fmaf(-2.0f, xy, xsr[m][j] + ysc[n]), 0.0f);
        float e = exp2r(d2 * C3) + exp2r(d2 * C4);
        if (__any(d2 < 210.0f)) {
          e += exp2r(d2 * C0) + exp2r(d2 * C1) + exp2r(d2 * C2);
        }
        bool skip = maskDiag && ((rbase + m * 16 + j) == (cbase + n * 16));
        sum += skip ? 0.0f : e;
      }

#pragma unroll
  for (int off = 32; off > 0; off >>= 1) sum += __shfl_down(sum, off);
  if (lane == 0) wsum[wid] = sum;
  __syncthreads();
  if (tid == 0) {
    double t = (double)((wsum[0] + wsum[1]) + (wsum[2] + wsum[3])) * (double)wt;
    atomicAdd(&accum[accIdx], t);
  }
}

__global__ void finalize_kernel(const double* __restrict__ accum,
                                float* __restrict__ out, int N, int M) {
  double dN = (double)N, dM = (double)M;
  double v = accum[0] / (5.0 * dN * dN) + accum[1] / (5.0 * dM * dM)
           - 2.0 * accum[2] / (5.0 * dN * dM) + 1.0 / dN + 1.0 / dM;
  out[0] = (float)v;
}

extern "C" void kernel_launch(void* const* d_in, const int* in_sizes, int n_in,
                              void* d_out, int out_size, void* d_ws, size_t ws_size,
                              hipStream_t stream) {
  const float* s = (const float*)d_in[0];
  const float* t = (const float*)d_in[1];
  int N = in_sizes[0] / D_FEAT;
  int M = in_sizes[1] / D_FEAT;

  char* ws = (char*)d_ws;
  unsigned short* Xb = (unsigned short*)ws;
  unsigned short* Yb = Xb + (size_t)N * D_FEAT;
  float* xsq = (float*)(Yb + (size_t)M * D_FEAT);
  float* ysq = xsq + N;
  double* accum = (double*)(((uintptr_t)(ysq + M) + 15) & ~(uintptr_t)15);

  hipMemsetAsync(accum, 0, 3 * sizeof(double), stream);
  prep_kernel<<<(N + 3) / 4, 256, 0, stream>>>(s, Xb, xsq, N);
  prep_kernel<<<(M + 3) / 4, 256, 0, stream>>>(t, Yb, ysq, M);

  int ntx = N / BM, nty = M / BM;
  int num_xy = ntx * nty;
  int num_tri_x = ntx * (ntx + 1) / 2;
  int num_tri_y = nty * (nty + 1) / 2;
  int grid = num_xy + num_tri_x + num_tri_y;
  mmd_pair_kernel<<<grid, 256, 0, stream>>>(Xb, Yb, xsq, ysq, accum,
                                            ntx, nty, num_xy, num_tri_x);
  finalize_kernel<<<1, 1, 0, stream>>>(accum, (float*)d_out, N, M);
}

// Round 3
// 131.062 us; speedup vs baseline: 1.6588x; 1.0597x over previous
//
#include <hip/hip_runtime.h>
#include <hip/hip_bf16.h>

#define D_FEAT 256
#define BM 128
#define BK 64

typedef float f32x4 __attribute__((ext_vector_type(4)));
typedef short bf16x8 __attribute__((ext_vector_type(8)));

// round-to-nearest-even f32 -> bf16 bits
__device__ __forceinline__ unsigned short f2bf(float f) {
  unsigned int u = __float_as_uint(f);
  u += 0x7fffu + ((u >> 16) & 1u);
  return (unsigned short)(u >> 16);
}

// raw v_exp_f32 (base-2). Input always <= 0 here; deep underflow -> 0.
__device__ __forceinline__ float exp2r(float x) {
  return __builtin_amdgcn_exp2f(x);
}

// Convert BOTH input matrices to bf16, compute exact f32 row sq-norms,
// and zero the 3 global accumulators. One wave per row.
__global__ void prep_kernel(const float* __restrict__ X,
                            const float* __restrict__ Y,
                            unsigned short* __restrict__ Xb,
                            unsigned short* __restrict__ Yb,
                            float* __restrict__ xsq, float* __restrict__ ysq,
                            double* __restrict__ accum, int N, int M) {
  if (blockIdx.x == 0 && threadIdx.x < 3) accum[threadIdx.x] = 0.0;
  int row = blockIdx.x * 4 + (threadIdx.x >> 6);
  int lane = threadIdx.x & 63;
  if (row >= N + M) return;
  const float* src; unsigned short* dst; float* sq; int r;
  if (row < N) { src = X; dst = Xb; sq = xsq; r = row; }
  else         { src = Y; dst = Yb; sq = ysq; r = row - N; }
  float4 v = reinterpret_cast<const float4*>(src)[r * (D_FEAT / 4) + lane];
  float s = v.x * v.x + v.y * v.y + v.z * v.z + v.w * v.w;
  ushort4 o;
  o.x = f2bf(v.x); o.y = f2bf(v.y); o.z = f2bf(v.z); o.w = f2bf(v.w);
  reinterpret_cast<ushort4*>(dst)[r * (D_FEAT / 4) + lane] = o;
#pragma unroll
  for (int off = 32; off > 0; off >>= 1) s += __shfl_down(s, off);
  if (lane == 0) sq[r] = s;
}

// Fused pair-tile kernel: bf16 MFMA Gram tile + multi-bandwidth gaussian
// epilogue + reduction. Grid covers xy (full) + xx/yy (upper triangular).
__global__ __launch_bounds__(256, 4)
void mmd_pair_kernel(const unsigned short* __restrict__ Xb,
                     const unsigned short* __restrict__ Yb,
                     const float* __restrict__ xsq,
                     const float* __restrict__ ysq,
                     double* __restrict__ accum,
                     int ntx, int nty, int num_xy, int num_tri_x) {
  __shared__ unsigned short As[BM * BK];
  __shared__ unsigned short Bs[BM * BK];
  __shared__ float wsum[4];

  int b = blockIdx.x;
  const unsigned short *Ap, *Bp;
  const float *asq, *bsq;
  int ti, tj, accIdx;
  float wt = 1.0f;
  bool maskDiag = false;

  if (b < num_xy) {
    ti = b / nty; tj = b % nty;
    Ap = Xb; Bp = Yb; asq = xsq; bsq = ysq; accIdx = 2;
  } else {
    int r, nt;
    if (b < num_xy + num_tri_x) {
      r = b - num_xy; nt = ntx; Ap = Xb; Bp = Xb; asq = xsq; bsq = xsq; accIdx = 0;
    } else {
      r = b - num_xy - num_tri_x; nt = nty; Ap = Yb; Bp = Yb; asq = ysq; bsq = ysq; accIdx = 1;
    }
    ti = 0;
    while (r >= nt - ti) { r -= nt - ti; ++ti; }  // upper-tri decode, ti<=tj
    tj = ti + r;
    if (ti == tj) maskDiag = true; else wt = 2.0f;
  }

  int tid = threadIdx.x;
  int wid = tid >> 6, lane = tid & 63;
  int wr = wid >> 1, wc = wid & 1;          // 2x2 wave grid, 64x64 per wave

  f32x4 acc[4][4];
#pragma unroll
  for (int m = 0; m < 4; ++m)
#pragma unroll
    for (int n = 0; n < 4; ++n) acc[m][n] = (f32x4){0.f, 0.f, 0.f, 0.f};

  const char* Abase = (const char*)Ap + (size_t)ti * BM * (D_FEAT * 2);
  const char* Bbase = (const char*)Bp + (size_t)tj * BM * (D_FEAT * 2);
  // staging geometry: chunk = 1KB = 8 rows x 128B; lane covers 16B
  int srow = lane >> 3;                     // row within chunk (0..7)
  int ssw = ((lane & 7) * 16) ^ (srow << 4); // pre-swizzled source col-byte

  for (int ks = 0; ks < D_FEAT / BK; ++ks) {
#pragma unroll
    for (int q = 0; q < 4; ++q) {
      int c = wid * 4 + q;                  // chunk id (0..15)
      size_t roff = (size_t)(c * 8 + srow) * (D_FEAT * 2) + ks * (BK * 2) + ssw;
      __builtin_amdgcn_global_load_lds(
          (const __attribute__((address_space(1))) unsigned int*)(Abase + roff),
          (__attribute__((address_space(3))) unsigned int*)((char*)As + c * 1024),
          16, 0, 0);
      __builtin_amdgcn_global_load_lds(
          (const __attribute__((address_space(1))) unsigned int*)(Bbase + roff),
          (__attribute__((address_space(3))) unsigned int*)((char*)Bs + c * 1024),
          16, 0, 0);
    }
    __syncthreads();
#pragma unroll
    for (int kk = 0; kk < 2; ++kk) {
      bf16x8 af[4], bfr[4];
#pragma unroll
      for (int m = 0; m < 4; ++m) {
        int rr = wr * 64 + m * 16 + (lane & 15);
        int colb = kk * 64 + (lane >> 4) * 16;
        int addr = rr * 128 + (colb ^ ((rr & 7) << 4));
        af[m] = *(const bf16x8*)((const char*)As + addr);
      }
#pragma unroll
      for (int n = 0; n < 4; ++n) {
        int rr = wc * 64 + n * 16 + (lane & 15);
        int colb = kk * 64 + (lane >> 4) * 16;
        int addr = rr * 128 + (colb ^ ((rr & 7) << 4));
        bfr[n] = *(const bf16x8*)((const char*)Bs + addr);
      }
#pragma unroll
      for (int m = 0; m < 4; ++m)
#pragma unroll
        for (int n = 0; n < 4; ++n)
          acc[m][n] = __builtin_amdgcn_mfma_f32_16x16x32_bf16(af[m], bfr[n], acc[m][n], 0, 0, 0);
    }
    __syncthreads();
  }

  // epilogue: d2 = |x|^2 + |y|^2 - 2*dot, 5-bandwidth gaussian sum
  // exp(c*d2) = exp2(d2 * c*log2(e)), c = -1/(2*bw^2)
  const float C0 = (float)(-18.033688010972094);   // bw 0.2
  const float C1 = (float)(-2.8853900817555354);   // bw 0.5
  const float C2 = (float)(-0.7213475204388839);   // bw 1.0
  const float C3 = (float)(-0.18033688010972097);  // bw 2.0
  const float C4 = (float)(-0.028853900817555354); // bw 5.0
  // For d2 > 210: C0..C2 args < -151 -> exactly 0 in f32 (below denorm min).
  // Bulk off-diagonal d2 ~ 512, so the 3-exp tail is group-uniformly skipped.

  int rbase = ti * BM + wr * 64 + (lane >> 4) * 4;
  int cbase = tj * BM + wc * 64 + (lane & 15);
  float xsr[4][4], ysc[4];
#pragma unroll
  for (int m = 0; m < 4; ++m)
#pragma unroll
    for (int j = 0; j < 4; ++j) xsr[m][j] = asq[rbase + m * 16 + j];
#pragma unroll
  for (int n = 0; n < 4; ++n) ysc[n] = bsq[cbase + n * 16];

  float sum = 0.f;
#pragma unroll
  for (int m = 0; m < 4; ++m)
#pragma unroll
    for (int n = 0; n < 4; ++n) {
      float d2v[4], es[4];
#pragma unroll
      for (int j = 0; j < 4; ++j)
        d2v[j] = fmaxf(fmaf(-2.0f, acc[m][n][j], xsr[m][j] + ysc[n]), 0.0f);
      float dmin = fminf(fminf(d2v[0], d2v[1]), fminf(d2v[2], d2v[3]));
#pragma unroll
      for (int j = 0; j < 4; ++j)
        es[j] = exp2r(d2v[j] * C3) + exp2r(d2v[j] * C4);
      if (__any(dmin < 210.0f)) {
#pragma unroll
        for (int j = 0; j < 4; ++j)
          es[j] += exp2r(d2v[j] * C0) + exp2r(d2v[j] * C1) + exp2r(d2v[j] * C2);
      }
      if (maskDiag) {
#pragma unroll
        for (int j = 0; j < 4; ++j)
          if ((rbase + m * 16 + j) == (cbase + n * 16)) es[j] = 0.0f;
      }
      sum += (es[0] + es[1]) + (es[2] + es[3]);
    }

#pragma unroll
  for (int off = 32; off > 0; off >>= 1) sum += __shfl_down(sum, off);
  if (lane == 0) wsum[wid] = sum;
  __syncthreads();
  if (tid == 0) {
    double t = (double)((wsum[0] + wsum[1]) + (wsum[2] + wsum[3])) * (double)wt;
    atomicAdd(&accum[accIdx], t);
  }
}

__global__ void finalize_kernel(const double* __restrict__ accum,
                                float* __restrict__ out, int N, int M) {
  double dN = (double)N, dM = (double)M;
  double v = accum[0] / (5.0 * dN * dN) + accum[1] / (5.0 * dM * dM)
           - 2.0 * accum[2] / (5.0 * dN * dM) + 1.0 / dN + 1.0 / dM;
  out[0] = (float)v;
}

extern "C" void kernel_launch(void* const* d_in, const int* in_sizes, int n_in,
                              void* d_out, int out_size, void* d_ws, size_t ws_size,
                              hipStream_t stream) {
  const float* s = (const float*)d_in[0];
  const float* t = (const float*)d_in[1];
  int N = in_sizes[0] / D_FEAT;
  int M = in_sizes[1] / D_FEAT;

  char* ws = (char*)d_ws;
  unsigned short* Xb = (unsigned short*)ws;
  unsigned short* Yb = Xb + (size_t)N * D_FEAT;
  float* xsq = (float*)(Yb + (size_t)M * D_FEAT);
  float* ysq = xsq + N;
  double* accum = (double*)(((uintptr_t)(ysq + M) + 15) & ~(uintptr_t)15);

  prep_kernel<<<(N + M + 3) / 4, 256, 0, stream>>>(s, t, Xb, Yb, xsq, ysq,
                                                   accum, N, M);

  int ntx = N / BM, nty = M / BM;
  int num_xy = ntx * nty;
  int num_tri_x = ntx * (ntx + 1) / 2;
  int num_tri_y = nty * (nty + 1) / 2;
  int grid = num_xy + num_tri_x + num_tri_y;
  mmd_pair_kernel<<<grid, 256, 0, stream>>>(Xb, Yb, xsq, ysq, accum,
                                            ntx, nty, num_xy, num_tri_x);
  finalize_kernel<<<1, 1, 0, stream>>>(accum, (float*)d_out, N, M);
}